// Round 9
// baseline (202.724 us; speedup 1.0000x reference)
//
#include <hip/hip_runtime.h>

// LengthRegulator: B=32, T=512, D=384, DUR_MAX=8, L = 512*7 = 3584
// R9: split pure-fill work from mixed work.
//   1) hipMemsetAsync zeroes the whole output (pure-store path, ~6.7 TB/s —
//      same path as the harness's own poison fill).
//   2) Content-only register scatter (R6 structure, tail phase deleted):
//      each of 2048 blocks owns 8 x-rows in registers (3 f32x4/thread),
//      recomputes the batch scan (L2-hot dur), stores each f4 e times into
//      its contiguous frame span [cum-e, cum). ~87 MiB writes + 24 MiB reads.
// mel_len tail written after memset by block c==0.

#define B_DIM 32
#define T_DIM 512
#define D_DIM 384
#define L_DIM 3584
#define VEC 96                          // f32x4 per row
#define RPB 8                           // rows per block
#define CHUNKS (T_DIM / RPB)            // 64
#define BLOCKS (B_DIM * CHUNKS)         // 2048 = 8 per CU, all resident

typedef float f32x4 __attribute__((ext_vector_type(4)));

__global__ void __launch_bounds__(256)
lr_content(const f32x4* __restrict__ x, const int* __restrict__ dur,
           f32x4* __restrict__ out, float* __restrict__ mel_out) {
    const int blk  = blockIdx.x;
    const int b    = blk >> 6;          // /CHUNKS
    const int c    = blk & 63;
    const int t    = threadIdx.x;       // 0..255
    const int lane = t & 63;
    const int wv   = t >> 6;            // 0..3

    // ---- full-batch scan: thread t owns tokens 2t, 2t+1 (L2-hot, 2 KB)
    const int2 dd = ((const int2*)(dur + b * T_DIM))[t];
    const int e0 = dd.x > 1 ? dd.x : 1;
    const int e1 = dd.y > 1 ? dd.y : 1;

    int val = e0 + e1;                  // wave inclusive scan of pair-sums
    #pragma unroll
    for (int off = 1; off < 64; off <<= 1) {
        int n = __shfl_up(val, off, 64);
        if (lane >= off) val += n;
    }

    __shared__ int wsum[4];
    __shared__ int scum[T_DIM];         // inclusive cumsum per token (2 KB)
    if (lane == 63) wsum[wv] = val;
    __syncthreads();

    int base = 0, tot = 0;
    #pragma unroll
    for (int i = 0; i < 4; ++i) {
        int w = wsum[i];
        tot += w;
        if (i < wv) base += w;
    }
    const int c1 = val + base;          // cum[2t+1]
    scum[2 * t]     = c1 - e1;
    scum[2 * t + 1] = c1;
    __syncthreads();

    if (c == 0 && t == 0)
        mel_out[b] = (float)tot;        // after memset in stream order

    // ---- register-resident content scatter of this block's 8 rows
    const int r0 = c * RPB;
    const f32x4* xb   = x + (size_t)(b * T_DIM + r0) * VEC;
    f32x4*       outb = out + (size_t)b * L_DIM * VEC;

    #pragma unroll
    for (int i = 0; i < 3; ++i) {       // 768 f4 / 256 threads
        const int v = t + i * 256;
        const int r = v / VEC;          // 0..7 (const divisor)
        const int w = v - r * VEC;
        const f32x4 xv = xb[v];         // coalesced, read exactly once
        const int gr = r0 + r;
        const int ce = scum[gr];        // broadcast LDS reads
        const int cs = (gr == 0) ? 0 : scum[gr - 1];
        f32x4* o = outb + (size_t)cs * VEC + w;
        for (int k = cs; k < ce; ++k) { // e in [1,7]; <=2 rows per wave
            *o = xv;
            o += VEC;
        }
    }
}

extern "C" void kernel_launch(void* const* d_in, const int* in_sizes, int n_in,
                              void* d_out, int out_size, void* d_ws, size_t ws_size,
                              hipStream_t stream) {
    const float* x   = (const float*)d_in[0];
    const int*   dur = (const int*)d_in[1];

    float* out     = (float*)d_out;
    float* mel_out = out + (size_t)B_DIM * L_DIM * D_DIM; // mel_len tail as f32

    // Phase 1: zero everything via the pure-fill path (~26 us for 176 MB).
    hipMemsetAsync(out, 0, (size_t)out_size * sizeof(float), stream);

    // Phase 2: content only (~87 MiB writes + 24 MiB reads).
    lr_content<<<dim3(BLOCKS), dim3(256), 0, stream>>>(
        (const f32x4*)x, dur, (f32x4*)out, mel_out);
}

// Round 10
// 191.243 us; speedup vs baseline: 1.0600x; 1.0600x over previous
//
#include <hip/hip_runtime.h>

// LengthRegulator: B=32, T=512, D=384, DUR_MAX=8, L = 512*7 = 3584
// R10 = R6 (best: fused single-dispatch register scatter) minus 3 overheads:
//   (a) x loads hoisted ABOVE the scan (overlap HBM latency with compute)
//   (b) scum[512] LDS round-trip -> 9-int exchange (block needs only
//       cum[r0-1..r0+7]; threads 4c..4c+3 own exactly those tokens)
//   (c) e-loop -> 7 predicated independent stores (no dependent ptr chain)
// Each of 2048 blocks: 8 x-rows in registers, scan batch durations (L2-hot),
// scatter rows to [cum-e,cum), balanced 1/64 slice of the zero tail.

#define B_DIM 32
#define T_DIM 512
#define D_DIM 384
#define L_DIM 3584
#define VEC 96                          // f32x4 per row
#define RPB 8                           // rows per block
#define CHUNKS (T_DIM / RPB)            // 64
#define BLOCKS (B_DIM * CHUNKS)         // 2048 = 8 per CU

typedef float f32x4 __attribute__((ext_vector_type(4)));

__global__ void __launch_bounds__(256)
lr_fused(const f32x4* __restrict__ x, const int* __restrict__ dur,
         f32x4* __restrict__ out, float* __restrict__ mel_out) {
    const int blk  = blockIdx.x;
    const int b    = blk >> 6;          // /CHUNKS
    const int c    = blk & 63;
    const int t    = threadIdx.x;       // 0..255
    const int lane = t & 63;
    const int wv   = t >> 6;            // 0..3
    const int r0   = c * RPB;

    // ---- (a) issue x row loads FIRST: independent of scan, hides HBM lat.
    const f32x4* xb = x + (size_t)(b * T_DIM + r0) * VEC;
    f32x4 xv0 = xb[t];
    f32x4 xv1 = xb[t + 256];
    f32x4 xv2 = xb[t + 512];

    // ---- scan: thread t owns tokens 2t, 2t+1 (dur slice is L2-hot)
    const int2 dd = ((const int2*)(dur + b * T_DIM))[t];
    const int e0 = dd.x > 1 ? dd.x : 1;
    const int e1 = dd.y > 1 ? dd.y : 1;

    int val = e0 + e1;                  // wave inclusive scan of pair-sums
    #pragma unroll
    for (int off = 1; off < 64; off <<= 1) {
        int n = __shfl_up(val, off, 64);
        if (lane >= off) val += n;
    }

    __shared__ int wsum[4];
    __shared__ int s[RPB + 1];          // cum[r0-1 .. r0+7]
    if (lane == 63) wsum[wv] = val;
    __syncthreads();

    int base = 0, tot = 0;
    #pragma unroll
    for (int i = 0; i < 4; ++i) {
        int w = wsum[i];
        tot += w;
        if (i < wv) base += w;
    }
    const int cum1 = val + base;        // cum of token 2t+1
    const int cum0 = cum1 - e1;         // cum of token 2t

    // ---- (b) 9-value cum exchange: threads 4c..4c+3 own tokens r0..r0+7
    if ((t >> 2) == c) {
        const int j = t & 3;
        s[2 * j + 1] = cum0;
        s[2 * j + 2] = cum1;
    }
    if (t == 4 * c - 1) s[0] = cum1;    // predecessor cum (token r0-1)
    if (c == 0 && t == 0) s[0] = 0;
    __syncthreads();

    const int mel = tot;
    if (c == 0 && t == 0)
        mel_out[b] = (float)mel;

    f32x4* outb = out + (size_t)b * L_DIM * VEC;

    // ---- (c) content scatter: 7 predicated independent stores per f4
    #pragma unroll
    for (int i = 0; i < 3; ++i) {
        const int v = t + i * 256;
        const int r = v / VEC;          // 0..7 (const divisor)
        const int w = v - r * VEC;
        const f32x4 xv = (i == 0) ? xv0 : (i == 1) ? xv1 : xv2;
        const int cs = s[r];
        const int ce = s[r + 1];        // e = ce-cs in [1,7]
        f32x4* o = outb + (size_t)cs * VEC + w;
        #pragma unroll
        for (int k = 0; k < 7; ++k)
            if (cs + k < ce)
                o[k * VEC] = xv;
    }

    // ---- balanced zero tail: 1/64 slice of [mel, L)
    const int tailspan = L_DIM - mel;   // 0..3072
    const int lo = mel + ((tailspan * c) >> 6);
    const int hi = mel + ((tailspan * (c + 1)) >> 6);
    const int n4 = (hi - lo) * VEC;
    const f32x4 z = (f32x4)0.f;
    f32x4* ob = outb + (size_t)lo * VEC;
    for (int v = t; v < n4; v += 256)
        ob[v] = z;
}

extern "C" void kernel_launch(void* const* d_in, const int* in_sizes, int n_in,
                              void* d_out, int out_size, void* d_ws, size_t ws_size,
                              hipStream_t stream) {
    const float* x   = (const float*)d_in[0];
    const int*   dur = (const int*)d_in[1];

    float* out     = (float*)d_out;
    float* mel_out = out + (size_t)B_DIM * L_DIM * D_DIM; // mel_len tail as f32

    lr_fused<<<dim3(BLOCKS), dim3(256), 0, stream>>>(
        (const f32x4*)x, dur, (f32x4*)out, mel_out);
}